// Round 1
// baseline (473.863 us; speedup 1.0000x reference)
//
#include <hip/hip_runtime.h>

typedef unsigned short u16;
typedef short short8 __attribute__((ext_vector_type(8)));
typedef float f32x4 __attribute__((ext_vector_type(4)));

// Problem constants (fixed by setup_inputs)
//   EMBED=256, NH=8, HD=32, NPAIR=16, K_PER_Q=164 (3^2+5^2+7^2+9^2)
//   levels: 128,64,32,16 ; compact rows/batch = 16384+4096+1024+256 = 21760
#define ROWS_PER_BATCH 21760
#define TOT_ROWS 43520

__device__ __forceinline__ u16 f2bf(float f){
  unsigned u = __builtin_bit_cast(unsigned, f);
  u += 0x7FFFu + ((u >> 16) & 1u);           // RNE
  return (u16)(u >> 16);
}
__device__ __forceinline__ float bf2f(u16 h){
  unsigned u = ((unsigned)h) << 16;
  return __builtin_bit_cast(float, u);
}
__device__ __forceinline__ float bflo(unsigned u){ return __builtin_bit_cast(float, u << 16); }
__device__ __forceinline__ float bfhi(unsigned u){ return __builtin_bit_cast(float, u & 0xFFFF0000u); }

// ---------- transpose + cast weights: WT[n][k] = W[k][n] in bf16 ----------
__global__ void wt_kernel(const float* __restrict__ kw, const float* __restrict__ vw,
                          u16* __restrict__ wtk, u16* __restrict__ wtv){
  int e = blockIdx.x * 256 + threadIdx.x;   // 0..131071
  int which = e >> 16;
  int r = e & 65535;
  int n = r >> 8, k = r & 255;
  const float* src = which ? vw : kw;
  u16* dst = which ? wtv : wtk;
  dst[r] = f2bf(src[k * 256 + n]);
}

// ---------- K/V map projection: compact rows (43520) x 256, bf16 MFMA ----------
// block: 256 thr = 4 waves; block tile = 64 rows x 64 cols of one output matrix
__global__ __launch_bounds__(256) void kv_gemm(const float* __restrict__ fm,
        const u16* __restrict__ wtk, const u16* __restrict__ wtv,
        u16* __restrict__ kmap, u16* __restrict__ vmap){
  __shared__ u16 Alds[64][264];              // +8 pad -> 2-way bank aliasing only
  const int t = threadIdx.x;
  const int row0 = blockIdx.x * 64;
  const int strip = blockIdx.y;              // 0..7 : 0-3 -> K, 4-7 -> V
  const u16* wt = (strip < 4) ? wtk : wtv;
  u16* outp = (strip < 4) ? kmap : vmap;
  const int colbase = (strip & 3) * 64;

  // decode (batch, level) for this row block — region boundaries are all %64==0
  const int b = row0 / ROWS_PER_BATCH;
  const int rr = row0 - b * ROWS_PER_BATCH;
  int l, loff;
  if (rr < 16384)      { l = 0; loff = 0; }
  else if (rr < 20480) { l = 1; loff = 16384; }
  else if (rr < 21504) { l = 2; loff = 20480; }
  else                 { l = 3; loff = 21504; }
  const int logW = 7 - l;
  const int Wm1 = (128 >> l) - 1;
  const int cell0 = rr - loff;
  const float* fmbase = fm + (size_t)(b * 4 + l) * (128 * 128 * 256);

  // stage A: 64 rows x 256 dims, fp32 -> bf16
  for (int i = 0; i < 16; ++i){
    int chunk = i * 256 + t;                 // 0..4095 float4 chunks
    int lr = chunk >> 6;
    int c4 = chunk & 63;
    int cell = cell0 + lr;
    int y = cell >> logW;
    int x = cell & Wm1;
    const float4 v = *(const float4*)(fmbase + ((((y << 7) + x) << 8) + c4 * 4));
    u16* d = &Alds[lr][c4 * 4];
    d[0] = f2bf(v.x); d[1] = f2bf(v.y); d[2] = f2bf(v.z); d[3] = f2bf(v.w);
  }
  __syncthreads();

  const int wv = t >> 6;
  const int lane = t & 63;
  const int mn = lane & 15;                  // A-row / B-col within tile
  const int quad = lane >> 4;
  f32x4 acc[4];
  #pragma unroll
  for (int i = 0; i < 4; ++i) acc[i] = (f32x4){0.f, 0.f, 0.f, 0.f};

  for (int kk = 0; kk < 8; ++kk){
    const int k0 = kk * 32;
    short8 a = *(const short8*)&Alds[wv * 16 + mn][k0 + quad * 8];
    #pragma unroll
    for (int tile = 0; tile < 4; ++tile){
      int col = colbase + tile * 16 + mn;
      short8 bfr = *(const short8*)(wt + col * 256 + k0 + quad * 8);
      acc[tile] = __builtin_amdgcn_mfma_f32_16x16x32_bf16(a, bfr, acc[tile], 0, 0, 0);
    }
  }
  #pragma unroll
  for (int tile = 0; tile < 4; ++tile){
    int col = colbase + tile * 16 + mn;
    #pragma unroll
    for (int r = 0; r < 4; ++r){
      int row = row0 + wv * 16 + quad * 4 + r;   // C/D: col=lane&15, row=quad*4+reg
      outp[(size_t)row * 256 + col] = f2bf(acc[tile][r]);
    }
  }
}

// ---------- fused per-query: LN -> qproj -> RoPE -> logits -> softmax -> PV -> outproj ----------
__global__ __launch_bounds__(256) void attn_kernel(
    const float* __restrict__ query, const float* __restrict__ qsp,
    const float* __restrict__ norm_w, const float* __restrict__ norm_b,
    const float* __restrict__ q_w, const float* __restrict__ out_w,
    const float* __restrict__ rope, const int* __restrict__ qbo, int nbo,
    const u16* __restrict__ kmap, const u16* __restrict__ vmap,
    float* __restrict__ out){
  __shared__ float sh_a[256];     // x, then q_rot (scaled)
  __shared__ float sh_b[256];     // q (pre-rope), then attn-weighted V
  __shared__ float sh_lg[8][164];
  __shared__ int   sh_row[164];
  __shared__ float sh_inv[8];
  __shared__ float sh_red[8];
  __shared__ float sh_rf[48];
  const int t = threadIdx.x;
  const int qi = blockIdx.x;
  if (t < 48) sh_rf[t] = rope[t];

  int bidx = 0;
  for (int j = 1; j < nbo; ++j) if (qi >= qbo[j]) bidx = j;
  const float p0 = qsp[qi * 2 + 0];
  const float p1 = qsp[qi * 2 + 1];

  // --- LayerNorm ---
  const float qv = query[qi * 256 + t];
  float s1 = qv, s2 = qv * qv;
  #pragma unroll
  for (int o = 32; o > 0; o >>= 1){
    s1 += __shfl_down(s1, o);
    s2 += __shfl_down(s2, o);
  }
  const int wv = t >> 6, lane = t & 63;
  if (lane == 0){ sh_red[wv] = s1; sh_red[4 + wv] = s2; }
  __syncthreads();
  if (t == 0){
    float a = sh_red[0] + sh_red[1] + sh_red[2] + sh_red[3];
    float bsum = sh_red[4] + sh_red[5] + sh_red[6] + sh_red[7];
    float mu = a * (1.0f / 256.0f);
    float var = bsum * (1.0f / 256.0f) - mu * mu;
    sh_red[0] = mu;
    sh_red[1] = rsqrtf(var + 1e-5f);
  }
  __syncthreads();
  sh_a[t] = (qv - sh_red[0]) * sh_red[1] * norm_w[t] + norm_b[t];
  __syncthreads();

  // --- q projection (fp32 vector) ---
  float accq = 0.f;
  for (int d = 0; d < 256; ++d) accq += sh_a[d] * q_w[d * 256 + t];
  sh_b[t] = accq;
  __syncthreads();

  // --- q RoPE, fold 1/sqrt(32) ---
  {
    int p = (t & 31) >> 1;
    float ang = p0 * sh_rf[p] + p1 * sh_rf[16 + p];   // level term is 0 for q
    float c = __cosf(ang), s = __sinf(ang);
    float x1 = sh_b[t & ~1], x2 = sh_b[t | 1];
    float v = (t & 1) ? (x1 * s + x2 * c) : (x1 * c - x2 * s);
    sh_a[t] = v * 0.17677669529663687f;               // 1/sqrt(HD)
  }
  __syncthreads();

  // --- logits: one thread per key ---
  if (t < 164){
    int l, dy, dx, loff;
    if (t < 9)       { l = 0; int j = t;      dy = j / 3 - 1; dx = j % 3 - 1; loff = 0; }
    else if (t < 34) { l = 1; int j = t - 9;  dy = j / 5 - 2; dx = j % 5 - 2; loff = 16384; }
    else if (t < 83) { l = 2; int j = t - 34; dy = j / 7 - 3; dx = j % 7 - 3; loff = 20480; }
    else             { l = 3; int j = t - 83; dy = j / 9 - 4; dx = j % 9 - 4; loff = 21504; }
    float sc = 1.0f / (float)(1 << l);                // exact 2^-l
    int c0 = (int)floorf(p0 * sc);
    int c1 = (int)floorf(p1 * sc);
    int i0 = c0 + dy, i1 = c1 + dx;
    int W = 128 >> l;
    if (i0 < 0 || i0 >= W || i1 < 0 || i1 >= W){
      sh_row[t] = -1;
      #pragma unroll
      for (int h = 0; h < 8; ++h) sh_lg[h][t] = -1e9f;
    } else {
      int row = bidx * ROWS_PER_BATCH + loff + (i0 << (7 - l)) + i1;
      sh_row[t] = row;
      float fs = (float)(1 << l);
      float kx = ((float)i0 + 0.5f) * fs;
      float ky = ((float)i1 + 0.5f) * fs;
      float lf = (float)l;
      float cs[16], sn[16];
      #pragma unroll
      for (int p = 0; p < 16; ++p){
        float ang = kx * sh_rf[p] + ky * sh_rf[16 + p] + lf * sh_rf[32 + p];
        cs[p] = __cosf(ang);
        sn[p] = __sinf(ang);
      }
      const unsigned* kp = (const unsigned*)(kmap + (size_t)row * 256);
      for (int h = 0; h < 8; ++h){
        const uint4* hp = (const uint4*)(kp + h * 16);
        uint4 a0 = hp[0], a1 = hp[1], a2 = hp[2], a3 = hp[3];
        unsigned u[16];
        u[0]=a0.x; u[1]=a0.y; u[2]=a0.z; u[3]=a0.w;
        u[4]=a1.x; u[5]=a1.y; u[6]=a1.z; u[7]=a1.w;
        u[8]=a2.x; u[9]=a2.y; u[10]=a2.z; u[11]=a2.w;
        u[12]=a3.x; u[13]=a3.y; u[14]=a3.z; u[15]=a3.w;
        float lg = 0.f;
        #pragma unroll
        for (int p = 0; p < 16; ++p){
          float k1 = bflo(u[p]), k2 = bfhi(u[p]);
          float r1 = k1 * cs[p] - k2 * sn[p];
          float r2 = k1 * sn[p] + k2 * cs[p];
          lg += sh_a[h * 32 + 2 * p] * r1 + sh_a[h * 32 + 2 * p + 1] * r2;
        }
        sh_lg[h][t] = lg;
      }
    }
  }
  __syncthreads();

  // --- softmax per head (invalid keys: exp(-1e9 - m) == 0 in fp32) ---
  if (t < 8){
    float m = -1e30f;
    for (int kk = 0; kk < 164; ++kk) m = fmaxf(m, sh_lg[t][kk]);
    float ssum = 0.f;
    for (int kk = 0; kk < 164; ++kk){
      float e = __expf(sh_lg[t][kk] - m);
      sh_lg[t][kk] = e;
      ssum += e;
    }
    sh_inv[t] = 1.0f / ssum;
  }
  __syncthreads();

  // --- attn @ V : thread t owns output dim t (coalesced V reads) ---
  {
    int h = t >> 5;
    float acc = 0.f;
    for (int kk = 0; kk < 164; ++kk){
      int row = sh_row[kk];
      if (row >= 0){
        acc += sh_lg[h][kk] * bf2f(vmap[(size_t)row * 256 + t]);
      }
    }
    sh_b[t] = acc * sh_inv[h];
  }
  __syncthreads();

  // --- out projection + residual ---
  float o = 0.f;
  for (int d = 0; d < 256; ++d) o += sh_b[d] * out_w[d * 256 + t];
  out[qi * 256 + t] = o + qv;
}

extern "C" void kernel_launch(void* const* d_in, const int* in_sizes, int n_in,
                              void* d_out, int out_size, void* d_ws, size_t ws_size,
                              hipStream_t stream) {
  (void)n_in; (void)out_size; (void)ws_size;
  const float* query  = (const float*)d_in[0];
  const float* qsp    = (const float*)d_in[1];
  const float* fm     = (const float*)d_in[2];
  const float* norm_w = (const float*)d_in[3];
  const float* norm_b = (const float*)d_in[4];
  const float* q_w    = (const float*)d_in[5];
  const float* k_w    = (const float*)d_in[6];
  const float* v_w    = (const float*)d_in[7];
  const float* out_w  = (const float*)d_in[8];
  const float* rope   = (const float*)d_in[9];
  const int*   qbo    = (const int*)d_in[10];
  float* out = (float*)d_out;
  const int n_q = in_sizes[0] / 256;
  const int nbo = in_sizes[10];

  // workspace: kmap | vmap | wtk | wtv  (~44.8 MB)
  u16* kmap = (u16*)d_ws;
  u16* vmap = kmap + (size_t)TOT_ROWS * 256;
  u16* wtk  = vmap + (size_t)TOT_ROWS * 256;
  u16* wtv  = wtk + 65536;

  hipLaunchKernelGGL(wt_kernel, dim3(512), dim3(256), 0, stream, k_w, v_w, wtk, wtv);
  hipLaunchKernelGGL(kv_gemm, dim3(TOT_ROWS / 64, 8), dim3(256), 0, stream,
                     fm, wtk, wtv, kmap, vmap);
  hipLaunchKernelGGL(attn_kernel, dim3(n_q), dim3(256), 0, stream,
                     query, qsp, norm_w, norm_b, q_w, out_w, rope, qbo, nbo,
                     kmap, vmap, out);
}

// Round 2
// 337.401 us; speedup vs baseline: 1.4044x; 1.4044x over previous
//
#include <hip/hip_runtime.h>
#include <hip/hip_bf16.h>

typedef unsigned short u16;
typedef short short8 __attribute__((ext_vector_type(8)));
typedef float f32x4 __attribute__((ext_vector_type(4)));

// EMBED=256, NH=8, HD=32, NPAIR=16, K_PER_Q=164; levels 128,64,32,16
// compact rows/batch = 16384+4096+1024+256 = 21760
#define ROWS_PER_BATCH 21760
#define TOT_ROWS 43520

__device__ __forceinline__ u16 f2bf(float f){
  unsigned u = __builtin_bit_cast(unsigned, f);
  u += 0x7FFFu + ((u >> 16) & 1u);
  return (u16)(u >> 16);
}
__device__ __forceinline__ float bf2f(u16 h){
  return __builtin_bit_cast(float, ((unsigned)h) << 16);
}
__device__ __forceinline__ float bflo(unsigned u){ return __builtin_bit_cast(float, u << 16); }
__device__ __forceinline__ float bfhi(unsigned u){ return __builtin_bit_cast(float, u & 0xFFFF0000u); }
__device__ __forceinline__ unsigned pk2bf(float a, float b){
  __hip_bfloat162 h = __float22bfloat162_rn(make_float2(a, b));
  union { __hip_bfloat162 h2; unsigned u; } cv; cv.h2 = h; return cv.u;
}

// ---------- transpose + cast all 4 weight matrices: WT[n][k] = W[k][n] bf16 ----------
__global__ __launch_bounds__(256) void wt_kernel(
    const float* __restrict__ qw, const float* __restrict__ kw,
    const float* __restrict__ vw, const float* __restrict__ ow,
    u16* __restrict__ wtq, u16* __restrict__ wtk,
    u16* __restrict__ wtv, u16* __restrict__ wto){
  int e = blockIdx.x * 256 + threadIdx.x;      // 0..262143
  int which = e >> 16;
  int r = e & 65535;
  int n = r >> 8, k = r & 255;
  const float* s = which == 0 ? qw : which == 1 ? kw : which == 2 ? vw : ow;
  u16* d       = which == 0 ? wtq : which == 1 ? wtk : which == 2 ? wtv : wto;
  d[r] = f2bf(s[k * 256 + n]);
}

// ---------- LayerNorm: 4 rows/block, one wave per row, output bf16 ----------
__global__ __launch_bounds__(256) void ln_kernel(
    const float* __restrict__ q, const float* __restrict__ w,
    const float* __restrict__ b, u16* __restrict__ x){
  const int t = threadIdx.x;
  const int row = blockIdx.x * 4 + (t >> 6);
  const int lane = t & 63;
  const float4 v = *(const float4*)(q + (size_t)row * 256 + lane * 4);
  float s1 = v.x + v.y + v.z + v.w;
  float s2 = v.x*v.x + v.y*v.y + v.z*v.z + v.w*v.w;
  #pragma unroll
  for (int o = 32; o > 0; o >>= 1){
    s1 += __shfl_xor(s1, o);
    s2 += __shfl_xor(s2, o);
  }
  float mu = s1 * (1.0f / 256.0f);
  float var = s2 * (1.0f / 256.0f) - mu * mu;
  float rs = rsqrtf(var + 1e-5f);
  const float4 wv = *(const float4*)(w + lane * 4);
  const float4 bv = *(const float4*)(b + lane * 4);
  float o0 = (v.x - mu) * rs * wv.x + bv.x;
  float o1 = (v.y - mu) * rs * wv.y + bv.y;
  float o2 = (v.z - mu) * rs * wv.z + bv.z;
  float o3 = (v.w - mu) * rs * wv.w + bv.w;
  uint2 pk = { pk2bf(o0, o1), pk2bf(o2, o3) };
  *(uint2*)(x + (size_t)row * 256 + lane * 4) = pk;
}

// ---------- K/V map projection + fused K-RoPE. grid (680, 2): y=0 -> K(rot), y=1 -> V ----------
__global__ __launch_bounds__(256) void kv_gemm(const float* __restrict__ fm,
        const u16* __restrict__ wtk, const u16* __restrict__ wtv,
        const float* __restrict__ rope,
        u16* __restrict__ krot, u16* __restrict__ vmap){
  __shared__ u16 Alds[64][264];
  __shared__ float2 sh_cs[64][16];             // cos/sin per (row, pair), K only
  const int t = threadIdx.x;
  const int row0 = blockIdx.x * 64;
  const int strip = blockIdx.y;                // 0 -> K, 1 -> V

  const int b = row0 / ROWS_PER_BATCH;
  const int rr = row0 - b * ROWS_PER_BATCH;
  int l, loff;
  if (rr < 16384)      { l = 0; loff = 0; }
  else if (rr < 20480) { l = 1; loff = 16384; }
  else if (rr < 21504) { l = 2; loff = 20480; }
  else                 { l = 3; loff = 21504; }
  const int logW = 7 - l;
  const int Wm1 = (128 >> l) - 1;
  const int cell0 = rr - loff;
  const float* fmbase = fm + (size_t)(b * 4 + l) * (128 * 128 * 256);

  // stage 64 rows x 256 dims fp32 -> bf16 (coalesced 1KB/wave float4 loads)
  for (int i = 0; i < 16; ++i){
    int chunk = i * 256 + t;
    int lr = chunk >> 6;
    int c4 = chunk & 63;
    int cell = cell0 + lr;
    int y = cell >> logW;
    int x = cell & Wm1;
    const float4 v = *(const float4*)(fmbase + ((((y << 7) + x) << 8) + c4 * 4));
    uint2 pk = { pk2bf(v.x, v.y), pk2bf(v.z, v.w) };
    *(uint2*)&Alds[lr][c4 * 4] = pk;
  }
  if (strip == 0){
    // cos/sin table: 1024 (row,pair) entries
    #pragma unroll
    for (int i = 0; i < 4; ++i){
      int id = i * 256 + t;
      int lr = id >> 4, p = id & 15;
      int cell = cell0 + lr;
      int i0 = cell >> logW;
      int i1 = cell & Wm1;
      float fs = (float)(1 << l);
      float kx = ((float)i0 + 0.5f) * fs;
      float ky = ((float)i1 + 0.5f) * fs;
      float ang = kx * rope[p] + ky * rope[16 + p] + (float)l * rope[32 + p];
      sh_cs[lr][p] = make_float2(__cosf(ang), __sinf(ang));
    }
  }
  __syncthreads();

  const u16* wt = (strip == 0) ? wtk : wtv;
  u16* outp = (strip == 0) ? krot : vmap;
  const int wv = t >> 6;
  const int lane = t & 63;
  const int mn = lane & 15;
  const int quad = lane >> 4;

  // hoist A fragments (reused across 4 col-strips)
  short8 af[8];
  #pragma unroll
  for (int kk = 0; kk < 8; ++kk)
    af[kk] = *(const short8*)&Alds[wv * 16 + mn][kk * 32 + quad * 8];

  for (int cs = 0; cs < 4; ++cs){
    const int colbase = cs * 64;
    f32x4 acc[4];
    #pragma unroll
    for (int i = 0; i < 4; ++i) acc[i] = (f32x4){0.f, 0.f, 0.f, 0.f};
    for (int kk = 0; kk < 8; ++kk){
      const int k0 = kk * 32;
      #pragma unroll
      for (int tile = 0; tile < 4; ++tile){
        int col = colbase + tile * 16 + mn;
        short8 bfr = *(const short8*)(wt + col * 256 + k0 + quad * 8);
        acc[tile] = __builtin_amdgcn_mfma_f32_16x16x32_bf16(af[kk], bfr, acc[tile], 0, 0, 0);
      }
    }
    #pragma unroll
    for (int tile = 0; tile < 4; ++tile){
      int col = colbase + tile * 16 + mn;
      #pragma unroll
      for (int r = 0; r < 4; ++r){
        int lr = wv * 16 + quad * 4 + r;
        float val = acc[tile][r];
        if (strip == 0){
          float partner = __shfl_xor(val, 1);    // adjacent col lives in lane^1
          float2 cssn = sh_cs[lr][(col & 31) >> 1];
          val = val * cssn.x + partner * ((col & 1) ? cssn.y : -cssn.y);
        }
        outp[(size_t)(row0 + lr) * 256 + col] = f2bf(val);
      }
    }
  }
}

// ---------- generic 64x32-tile MFMA GEMM: out[M][256] = A(bf16) @ WT + resid ----------
__global__ __launch_bounds__(256) void gemm_xw(const u16* __restrict__ A,
        const u16* __restrict__ wt, const float* __restrict__ resid,
        float* __restrict__ out){
  __shared__ u16 Alds[64][264];
  const int t = threadIdx.x;
  const int row0 = blockIdx.x * 64;
  const int colbase = blockIdx.y * 32;
  #pragma unroll
  for (int i = 0; i < 8; ++i){
    int chunk = i * 256 + t;
    int lr = chunk >> 5;
    int c8 = chunk & 31;
    uint4 v = *(const uint4*)(A + (size_t)(row0 + lr) * 256 + c8 * 8);
    *(uint4*)&Alds[lr][c8 * 8] = v;
  }
  __syncthreads();
  const int wv = t >> 6;
  const int lane = t & 63;
  const int mn = lane & 15;
  const int quad = lane >> 4;
  f32x4 acc[2];
  acc[0] = (f32x4){0.f,0.f,0.f,0.f};
  acc[1] = (f32x4){0.f,0.f,0.f,0.f};
  for (int kk = 0; kk < 8; ++kk){
    const int k0 = kk * 32;
    short8 a = *(const short8*)&Alds[wv * 16 + mn][k0 + quad * 8];
    #pragma unroll
    for (int tile = 0; tile < 2; ++tile){
      int col = colbase + tile * 16 + mn;
      short8 bfr = *(const short8*)(wt + col * 256 + k0 + quad * 8);
      acc[tile] = __builtin_amdgcn_mfma_f32_16x16x32_bf16(a, bfr, acc[tile], 0, 0, 0);
    }
  }
  #pragma unroll
  for (int tile = 0; tile < 2; ++tile){
    int col = colbase + tile * 16 + mn;
    #pragma unroll
    for (int r = 0; r < 4; ++r){
      int row = row0 + wv * 16 + quad * 4 + r;
      float val = acc[tile][r];
      if (resid) val += resid[(size_t)row * 256 + col];
      out[(size_t)row * 256 + col] = val;
    }
  }
}

// ---------- attention core: q-RoPE -> logits (head-parallel) -> softmax -> PV ----------
__global__ __launch_bounds__(256) void attn2(
    const float* __restrict__ qraw, const float* __restrict__ qsp,
    const float* __restrict__ rope, const int* __restrict__ qbo, int nbo,
    const u16* __restrict__ krot, const u16* __restrict__ vmap,
    u16* __restrict__ ao){
  __shared__ float sh_q[8][33];     // padded: bank-conflict-free per-head reads
  __shared__ float sh_lg[8][168];
  __shared__ int   sh_row[176];
  const int t = threadIdx.x;
  const int qi = blockIdx.x;

  int bidx = 0;
  for (int j = 1; j < nbo; ++j) if (qi >= qbo[j]) bidx = j;
  const float p0 = qsp[qi * 2 + 0];
  const float p1 = qsp[qi * 2 + 1];

  // q RoPE (scale 1/sqrt(32) folded in)
  {
    float qv = qraw[(size_t)qi * 256 + t];
    int p = (t & 31) >> 1;
    float ang = p0 * rope[p] + p1 * rope[16 + p];
    float c = __cosf(ang), s = __sinf(ang);
    float partner = __shfl_xor(qv, 1);
    float val = (t & 1) ? (partner * s + qv * c) : (qv * c - partner * s);
    sh_q[t >> 5][t & 31] = val * 0.17677669529663687f;
  }

  // key rows + validity
  if (t < 164){
    int l, dy, dx, loff;
    if (t < 9)       { l = 0; int j = t;      dy = j / 3 - 1; dx = j % 3 - 1; loff = 0; }
    else if (t < 34) { l = 1; int j = t - 9;  dy = j / 5 - 2; dx = j % 5 - 2; loff = 16384; }
    else if (t < 83) { l = 2; int j = t - 34; dy = j / 7 - 3; dx = j % 7 - 3; loff = 20480; }
    else             { l = 3; int j = t - 83; dy = j / 9 - 4; dx = j % 9 - 4; loff = 21504; }
    float sc = 1.0f / (float)(1 << l);
    int i0 = (int)floorf(p0 * sc) + dy;
    int i1 = (int)floorf(p1 * sc) + dx;
    int W = 128 >> l;
    sh_row[t] = (i0 < 0 || i0 >= W || i1 < 0 || i1 >= W)
              ? -1 : bidx * ROWS_PER_BATCH + loff + (i0 << (7 - l)) + i1;
  }
  __syncthreads();

  // logits: thread = (key kbase, head h); 8 consecutive threads read one 512B K row
  const int h = t & 7;
  const int kbase = t >> 3;
  float qreg[32];
  #pragma unroll
  for (int d = 0; d < 32; ++d) qreg[d] = sh_q[h][d];
  for (int pass = 0; pass < 6; ++pass){
    int kk = pass * 32 + kbase;
    if (kk < 164){
      int row = sh_row[kk];
      float lg = -1e9f;
      if (row >= 0){
        const uint4* kp = (const uint4*)(krot + (size_t)row * 256 + h * 32);
        uint4 A0 = kp[0], A1 = kp[1], A2 = kp[2], A3 = kp[3];
        unsigned uu[16];
        uu[0]=A0.x; uu[1]=A0.y; uu[2]=A0.z; uu[3]=A0.w;
        uu[4]=A1.x; uu[5]=A1.y; uu[6]=A1.z; uu[7]=A1.w;
        uu[8]=A2.x; uu[9]=A2.y; uu[10]=A2.z; uu[11]=A2.w;
        uu[12]=A3.x; uu[13]=A3.y; uu[14]=A3.z; uu[15]=A3.w;
        lg = 0.f;
        #pragma unroll
        for (int j = 0; j < 16; ++j)
          lg += qreg[2*j] * bflo(uu[j]) + qreg[2*j+1] * bfhi(uu[j]);
      }
      sh_lg[h][kk] = lg;
    }
  }
  __syncthreads();

  // softmax: 32 lanes per head, shuffle butterflies (xor<32 stays in head group)
  const int h3 = t >> 5;
  const int l32 = t & 31;
  float m = -1e30f;
  for (int kk = l32; kk < 164; kk += 32) m = fmaxf(m, sh_lg[h3][kk]);
  #pragma unroll
  for (int o = 16; o > 0; o >>= 1) m = fmaxf(m, __shfl_xor(m, o));
  float ssum = 0.f;
  for (int kk = l32; kk < 164; kk += 32){
    float e = __expf(sh_lg[h3][kk] - m);   // invalid keys -> exactly 0
    sh_lg[h3][kk] = e;
    ssum += e;
  }
  #pragma unroll
  for (int o = 16; o > 0; o >>= 1) ssum += __shfl_xor(ssum, o);
  const float inv = 1.0f / ssum;
  __syncthreads();

  // PV: thread t = output dim; branchless (e==0 for invalid rows)
  float acc = 0.f;
  #pragma unroll 4
  for (int kk = 0; kk < 164; ++kk){
    int row = sh_row[kk];
    int rc = row < 0 ? 0 : row;
    float e = sh_lg[h3][kk];
    acc += e * bf2f(vmap[(size_t)rc * 256 + t]);
  }
  ao[(size_t)qi * 256 + t] = f2bf(acc * inv);
}

extern "C" void kernel_launch(void* const* d_in, const int* in_sizes, int n_in,
                              void* d_out, int out_size, void* d_ws, size_t ws_size,
                              hipStream_t stream) {
  (void)n_in; (void)out_size; (void)ws_size;
  const float* query  = (const float*)d_in[0];
  const float* qsp    = (const float*)d_in[1];
  const float* fm     = (const float*)d_in[2];
  const float* norm_w = (const float*)d_in[3];
  const float* norm_b = (const float*)d_in[4];
  const float* q_w    = (const float*)d_in[5];
  const float* k_w    = (const float*)d_in[6];
  const float* v_w    = (const float*)d_in[7];
  const float* out_w  = (const float*)d_in[8];
  const float* rope   = (const float*)d_in[9];
  const int*   qbo    = (const int*)d_in[10];
  float* out = (float*)d_out;
  const int n_q = in_sizes[0] / 256;
  const int nbo = in_sizes[10];

  // workspace layout (bytes): krot | vmap | qraw(f32) | xbf/ao (shared) | 4x WT
  char* p = (char*)d_ws;
  u16* krot = (u16*)p;                       p += (size_t)TOT_ROWS * 256 * 2;
  u16* vmap = (u16*)p;                       p += (size_t)TOT_ROWS * 256 * 2;
  float* qraw = (float*)p;                   p += (size_t)n_q * 256 * 4;
  u16* xbf = (u16*)p;                        p += (size_t)n_q * 256 * 2;   // reused as ao
  u16* wtq = (u16*)p;                        p += 65536 * 2;
  u16* wtk = (u16*)p;                        p += 65536 * 2;
  u16* wtv = (u16*)p;                        p += 65536 * 2;
  u16* wto = (u16*)p;
  u16* ao = xbf;   // lifetimes disjoint: xbf dead after q-GEMM, ao born in attn2

  hipLaunchKernelGGL(wt_kernel, dim3(1024), dim3(256), 0, stream,
                     q_w, k_w, v_w, out_w, wtq, wtk, wtv, wto);
  hipLaunchKernelGGL(ln_kernel, dim3(n_q / 4), dim3(256), 0, stream,
                     query, norm_w, norm_b, xbf);
  hipLaunchKernelGGL(kv_gemm, dim3(TOT_ROWS / 64, 2), dim3(256), 0, stream,
                     fm, wtk, wtv, rope, krot, vmap);
  hipLaunchKernelGGL(gemm_xw, dim3(n_q / 64, 8), dim3(256), 0, stream,
                     xbf, wtq, (const float*)nullptr, qraw);
  hipLaunchKernelGGL(attn2, dim3(n_q), dim3(256), 0, stream,
                     qraw, qsp, rope, qbo, nbo, krot, vmap, ao);
  hipLaunchKernelGGL(gemm_xw, dim3(n_q / 64, 8), dim3(256), 0, stream,
                     ao, wto, query, out);
}

// Round 3
// 308.053 us; speedup vs baseline: 1.5382x; 1.0953x over previous
//
#include <hip/hip_runtime.h>
#include <hip/hip_bf16.h>

typedef unsigned short u16;
typedef short short8 __attribute__((ext_vector_type(8)));
typedef float f32x4 __attribute__((ext_vector_type(4)));

// EMBED=256, NH=8, HD=32, NPAIR=16, K_PER_Q=164; levels 128,64,32,16
// compact rows/batch = 16384+4096+1024+256 = 21760
#define ROWS_PER_BATCH 21760
#define TOT_ROWS 43520

__device__ __forceinline__ u16 f2bf(float f){
  unsigned u = __builtin_bit_cast(unsigned, f);
  u += 0x7FFFu + ((u >> 16) & 1u);
  return (u16)(u >> 16);
}
__device__ __forceinline__ float bf2f(u16 h){
  return __builtin_bit_cast(float, ((unsigned)h) << 16);
}
__device__ __forceinline__ float bflo(unsigned u){ return __builtin_bit_cast(float, u << 16); }
__device__ __forceinline__ float bfhi(unsigned u){ return __builtin_bit_cast(float, u & 0xFFFF0000u); }
__device__ __forceinline__ unsigned pk2bf(float a, float b){
  __hip_bfloat162 h = __float22bfloat162_rn(make_float2(a, b));
  union { __hip_bfloat162 h2; unsigned u; } cv; cv.h2 = h; return cv.u;
}

// ---------- weights -> bf16 in MFMA-fragment-packed order ----------
// packed[((cg*8 + kk)*64 + lane)*8 + j] = W[kk*32 + (lane>>4)*8 + j][cg*16 + (lane&15)]
// so a wave B-load (lane -> lane*16B) is 1KB contiguous.
__global__ __launch_bounds__(256) void wt_kernel(
    const float* __restrict__ qw, const float* __restrict__ kw,
    const float* __restrict__ vw, const float* __restrict__ ow,
    u16* __restrict__ wtq, u16* __restrict__ wtk,
    u16* __restrict__ wtv, u16* __restrict__ wto){
  int t = blockIdx.x * 256 + threadIdx.x;      // 0..32767 ; 8192 chunks/matrix
  int which = t >> 13;
  int r = t & 8191;
  int cg = r >> 9;
  int kk = (r >> 6) & 7;
  int lane = r & 63;
  int quad = lane >> 4, mn = lane & 15;
  const float* s = which == 0 ? qw : which == 1 ? kw : which == 2 ? vw : ow;
  u16* d       = which == 0 ? wtq : which == 1 ? wtk : which == 2 ? wtv : wto;
  const float* base = s + (kk * 32 + quad * 8) * 256 + cg * 16 + mn;
  float e[8];
  #pragma unroll
  for (int j = 0; j < 8; ++j) e[j] = base[j * 256];
  uint4 o = { pk2bf(e[0], e[1]), pk2bf(e[2], e[3]), pk2bf(e[4], e[5]), pk2bf(e[6], e[7]) };
  *(uint4*)(d + (size_t)r * 8) = o;
}

// ---------- LayerNorm: 4 rows/block, one wave per row, output bf16 ----------
__global__ __launch_bounds__(256) void ln_kernel(
    const float* __restrict__ q, const float* __restrict__ w,
    const float* __restrict__ b, u16* __restrict__ x){
  const int t = threadIdx.x;
  const int row = blockIdx.x * 4 + (t >> 6);
  const int lane = t & 63;
  const float4 v = *(const float4*)(q + (size_t)row * 256 + lane * 4);
  float s1 = v.x + v.y + v.z + v.w;
  float s2 = v.x*v.x + v.y*v.y + v.z*v.z + v.w*v.w;
  #pragma unroll
  for (int o = 32; o > 0; o >>= 1){
    s1 += __shfl_xor(s1, o);
    s2 += __shfl_xor(s2, o);
  }
  float mu = s1 * (1.0f / 256.0f);
  float var = s2 * (1.0f / 256.0f) - mu * mu;
  float rs = rsqrtf(var + 1e-5f);
  const float4 wv = *(const float4*)(w + lane * 4);
  const float4 bv = *(const float4*)(b + lane * 4);
  float o0 = (v.x - mu) * rs * wv.x + bv.x;
  float o1 = (v.y - mu) * rs * wv.y + bv.y;
  float o2 = (v.z - mu) * rs * wv.z + bv.z;
  float o3 = (v.w - mu) * rs * wv.w + bv.w;
  uint2 pk = { pk2bf(o0, o1), pk2bf(o2, o3) };
  *(uint2*)(x + (size_t)row * 256 + lane * 4) = pk;
}

// ---------- K+V map projection, fused K-RoPE, coalesced epilogue ----------
// 680 blocks x 256 thr; block = 64 rows, computes both K(rot) and V (A staged once).
__global__ __launch_bounds__(256) void kv_gemm(const float* __restrict__ fm,
        const u16* __restrict__ wtkp, const u16* __restrict__ wtvp,
        const float* __restrict__ rope,
        u16* __restrict__ krot, u16* __restrict__ vmap){
  // union: A tile (64x264 u16 = 33792B) then per-wave epilogue slabs [par][wv][16][66] f32
  __shared__ __align__(16) char smraw[33792];
  u16 (*Alds)[264] = (u16 (*)[264])smraw;
  typedef float eslab[16][66];
  eslab* epil = (eslab*)smraw;                 // index [par*4 + wv]
  __shared__ unsigned sh_cs[64][16];           // packed bf16 (cos, sin)

  const int t = threadIdx.x;
  const int row0 = blockIdx.x * 64;

  const int b = row0 / ROWS_PER_BATCH;
  const int rr = row0 - b * ROWS_PER_BATCH;
  int l, loff;
  if (rr < 16384)      { l = 0; loff = 0; }
  else if (rr < 20480) { l = 1; loff = 16384; }
  else if (rr < 21504) { l = 2; loff = 20480; }
  else                 { l = 3; loff = 21504; }
  const int logW = 7 - l;
  const int Wm1 = (128 >> l) - 1;
  const int cell0 = rr - loff;
  const float* fmbase = fm + (size_t)(b * 4 + l) * (128 * 128 * 256);

  // stage 64 rows x 256 dims fp32 -> bf16
  for (int i = 0; i < 16; ++i){
    int chunk = i * 256 + t;
    int lr = chunk >> 6;
    int c4 = chunk & 63;
    int cell = cell0 + lr;
    int y = cell >> logW;
    int x = cell & Wm1;
    const float4 v = *(const float4*)(fmbase + ((((y << 7) + x) << 8) + c4 * 4));
    uint2 pk = { pk2bf(v.x, v.y), pk2bf(v.z, v.w) };
    *(uint2*)&Alds[lr][c4 * 4] = pk;
  }
  // cos/sin table (bf16-packed): 1024 (row,pair) entries
  #pragma unroll
  for (int i = 0; i < 4; ++i){
    int id = i * 256 + t;
    int lr = id >> 4, p = id & 15;
    int cell = cell0 + lr;
    int i0 = cell >> logW;
    int i1 = cell & Wm1;
    float fs = (float)(1 << l);
    float kx = ((float)i0 + 0.5f) * fs;
    float ky = ((float)i1 + 0.5f) * fs;
    float ang = kx * rope[p] + ky * rope[16 + p] + (float)l * rope[32 + p];
    sh_cs[lr][p] = pk2bf(__cosf(ang), __sinf(ang));
  }
  __syncthreads();

  const int wv = t >> 6;
  const int lane = t & 63;
  const int mn = lane & 15;
  const int quad = lane >> 4;

  // hoist A fragments (Alds dead afterwards; region reused by epil)
  short8 af[8];
  #pragma unroll
  for (int kk = 0; kk < 8; ++kk)
    af[kk] = *(const short8*)&Alds[wv * 16 + mn][kk * 32 + quad * 8];
  __syncthreads();

  for (int m = 0; m < 2; ++m){
    const u16* wt = m ? wtvp : wtkp;
    u16* outp = m ? vmap : krot;
    for (int cs2 = 0; cs2 < 4; ++cs2){
      f32x4 acc[4];
      #pragma unroll
      for (int i = 0; i < 4; ++i) acc[i] = (f32x4){0.f, 0.f, 0.f, 0.f};
      for (int kk = 0; kk < 8; ++kk){
        #pragma unroll
        for (int tile = 0; tile < 4; ++tile){
          const short8 bfr = *(const short8*)(wt +
              ((size_t)(((cs2 * 4 + tile) * 8 + kk) * 64 + lane)) * 8);
          acc[tile] = __builtin_amdgcn_mfma_f32_16x16x32_bf16(af[kk], bfr, acc[tile], 0, 0, 0);
        }
      }
      const int par = (m * 4 + cs2) & 1;
      float (*sl)[66] = epil[par * 4 + wv];
      #pragma unroll
      for (int tile = 0; tile < 4; ++tile)
        #pragma unroll
        for (int r = 0; r < 4; ++r)
          sl[quad * 4 + r][tile * 16 + mn] = acc[tile][r];
      __syncthreads();
      // coalesced read-back: 512 pairs per wave-slab, 8 iters x float2
      #pragma unroll
      for (int i = 0; i < 8; ++i){
        int pi = i * 64 + lane;
        int row = pi >> 5;
        int pl = pi & 31;
        float2 kv2 = *(const float2*)&sl[row][pl * 2];
        unsigned o;
        if (m == 0){
          unsigned csn = sh_cs[wv * 16 + row][pl & 15];
          float c = bflo(csn), s = bfhi(csn);
          o = pk2bf(kv2.x * c - kv2.y * s, kv2.x * s + kv2.y * c);
        } else {
          o = pk2bf(kv2.x, kv2.y);
        }
        *(unsigned*)(outp + (size_t)(row0 + wv * 16 + row) * 256 + cs2 * 64 + pl * 2) = o;
      }
    }
  }
}

// ---------- 64x32-tile MFMA GEMM with packed B: out = A(bf16) @ WT + resid ----------
__global__ __launch_bounds__(256) void gemm_xw(const u16* __restrict__ A,
        const u16* __restrict__ wt, const float* __restrict__ resid,
        float* __restrict__ out){
  __shared__ u16 Alds[64][264];
  const int t = threadIdx.x;
  const int row0 = blockIdx.x * 64;
  #pragma unroll
  for (int i = 0; i < 8; ++i){
    int chunk = i * 256 + t;
    int lr = chunk >> 5;
    int c8 = chunk & 31;
    uint4 v = *(const uint4*)(A + (size_t)(row0 + lr) * 256 + c8 * 8);
    *(uint4*)&Alds[lr][c8 * 8] = v;
  }
  __syncthreads();
  const int wv = t >> 6;
  const int lane = t & 63;
  const int mn = lane & 15;
  const int quad = lane >> 4;
  f32x4 acc[2];
  acc[0] = (f32x4){0.f,0.f,0.f,0.f};
  acc[1] = (f32x4){0.f,0.f,0.f,0.f};
  for (int kk = 0; kk < 8; ++kk){
    short8 a = *(const short8*)&Alds[wv * 16 + mn][kk * 32 + quad * 8];
    #pragma unroll
    for (int tile = 0; tile < 2; ++tile){
      int cg = blockIdx.y * 2 + tile;
      const short8 bfr = *(const short8*)(wt + ((size_t)((cg * 8 + kk) * 64 + lane)) * 8);
      acc[tile] = __builtin_amdgcn_mfma_f32_16x16x32_bf16(a, bfr, acc[tile], 0, 0, 0);
    }
  }
  #pragma unroll
  for (int tile = 0; tile < 2; ++tile){
    int col = blockIdx.y * 32 + tile * 16 + mn;
    #pragma unroll
    for (int r = 0; r < 4; ++r){
      int row = row0 + wv * 16 + quad * 4 + r;
      float val = acc[tile][r];
      if (resid) val += resid[(size_t)row * 256 + col];
      out[(size_t)row * 256 + col] = val;
    }
  }
}

// ---------- attention core: q-RoPE -> logits (head-parallel) -> softmax -> PV ----------
__global__ __launch_bounds__(256) void attn2(
    const float* __restrict__ qraw, const float* __restrict__ qsp,
    const float* __restrict__ rope, const int* __restrict__ qbo, int nbo,
    const u16* __restrict__ krot, const u16* __restrict__ vmap,
    u16* __restrict__ ao){
  __shared__ float sh_q[8][33];
  __shared__ float sh_lg[8][168];
  __shared__ int   sh_row[176];
  const int t = threadIdx.x;
  const int qi = blockIdx.x;

  int bidx = 0;
  for (int j = 1; j < nbo; ++j) if (qi >= qbo[j]) bidx = j;
  const float p0 = qsp[qi * 2 + 0];
  const float p1 = qsp[qi * 2 + 1];

  // q RoPE (scale 1/sqrt(32) folded in)
  {
    float qv = qraw[(size_t)qi * 256 + t];
    int p = (t & 31) >> 1;
    float ang = p0 * rope[p] + p1 * rope[16 + p];
    float c = __cosf(ang), s = __sinf(ang);
    float partner = __shfl_xor(qv, 1);
    float val = (t & 1) ? (partner * s + qv * c) : (qv * c - partner * s);
    sh_q[t >> 5][t & 31] = val * 0.17677669529663687f;
  }

  if (t < 164){
    int l, dy, dx, loff;
    if (t < 9)       { l = 0; int j = t;      dy = j / 3 - 1; dx = j % 3 - 1; loff = 0; }
    else if (t < 34) { l = 1; int j = t - 9;  dy = j / 5 - 2; dx = j % 5 - 2; loff = 16384; }
    else if (t < 83) { l = 2; int j = t - 34; dy = j / 7 - 3; dx = j % 7 - 3; loff = 20480; }
    else             { l = 3; int j = t - 83; dy = j / 9 - 4; dx = j % 9 - 4; loff = 21504; }
    float sc = 1.0f / (float)(1 << l);
    int i0 = (int)floorf(p0 * sc) + dy;
    int i1 = (int)floorf(p1 * sc) + dx;
    int W = 128 >> l;
    sh_row[t] = (i0 < 0 || i0 >= W || i1 < 0 || i1 >= W)
              ? -1 : bidx * ROWS_PER_BATCH + loff + (i0 << (7 - l)) + i1;
  }
  __syncthreads();

  // logits: thread = (key, head); 8 consecutive threads read one 512B K row
  const int h = t & 7;
  const int kbase = t >> 3;
  float qreg[32];
  #pragma unroll
  for (int d = 0; d < 32; ++d) qreg[d] = sh_q[h][d];
  for (int pass = 0; pass < 6; ++pass){
    int kk = pass * 32 + kbase;
    if (kk < 164){
      int row = sh_row[kk];
      float lg = -1e9f;
      if (row >= 0){
        const uint4* kp = (const uint4*)(krot + (size_t)row * 256 + h * 32);
        uint4 A0 = kp[0], A1 = kp[1], A2 = kp[2], A3 = kp[3];
        unsigned uu[16];
        uu[0]=A0.x; uu[1]=A0.y; uu[2]=A0.z; uu[3]=A0.w;
        uu[4]=A1.x; uu[5]=A1.y; uu[6]=A1.z; uu[7]=A1.w;
        uu[8]=A2.x; uu[9]=A2.y; uu[10]=A2.z; uu[11]=A2.w;
        uu[12]=A3.x; uu[13]=A3.y; uu[14]=A3.z; uu[15]=A3.w;
        lg = 0.f;
        #pragma unroll
        for (int j = 0; j < 16; ++j)
          lg += qreg[2*j] * bflo(uu[j]) + qreg[2*j+1] * bfhi(uu[j]);
      }
      sh_lg[h][kk] = lg;
    }
  }
  __syncthreads();

  // softmax: 32 lanes per head
  const int h3 = t >> 5;
  const int l32 = t & 31;
  float m = -1e30f;
  for (int kk = l32; kk < 164; kk += 32) m = fmaxf(m, sh_lg[h3][kk]);
  #pragma unroll
  for (int o = 16; o > 0; o >>= 1) m = fmaxf(m, __shfl_xor(m, o));
  float ssum = 0.f;
  for (int kk = l32; kk < 164; kk += 32){
    float e = __expf(sh_lg[h3][kk] - m);
    sh_lg[h3][kk] = e;
    ssum += e;
  }
  #pragma unroll
  for (int o = 16; o > 0; o >>= 1) ssum += __shfl_xor(ssum, o);
  const float inv = 1.0f / ssum;
  __syncthreads();

  // PV: thread t = output dim
  float acc = 0.f;
  #pragma unroll 4
  for (int kk = 0; kk < 164; ++kk){
    int row = sh_row[kk];
    int rc = row < 0 ? 0 : row;
    float e = sh_lg[h3][kk];
    acc += e * bf2f(vmap[(size_t)rc * 256 + t]);
  }
  ao[(size_t)qi * 256 + t] = f2bf(acc * inv);
}

extern "C" void kernel_launch(void* const* d_in, const int* in_sizes, int n_in,
                              void* d_out, int out_size, void* d_ws, size_t ws_size,
                              hipStream_t stream) {
  (void)n_in; (void)out_size; (void)ws_size;
  const float* query  = (const float*)d_in[0];
  const float* qsp    = (const float*)d_in[1];
  const float* fm     = (const float*)d_in[2];
  const float* norm_w = (const float*)d_in[3];
  const float* norm_b = (const float*)d_in[4];
  const float* q_w    = (const float*)d_in[5];
  const float* k_w    = (const float*)d_in[6];
  const float* v_w    = (const float*)d_in[7];
  const float* out_w  = (const float*)d_in[8];
  const float* rope   = (const float*)d_in[9];
  const int*   qbo    = (const int*)d_in[10];
  float* out = (float*)d_out;
  const int n_q = in_sizes[0] / 256;
  const int nbo = in_sizes[10];

  char* p = (char*)d_ws;
  u16* krot = (u16*)p;                       p += (size_t)TOT_ROWS * 256 * 2;
  u16* vmap = (u16*)p;                       p += (size_t)TOT_ROWS * 256 * 2;
  float* qraw = (float*)p;                   p += (size_t)n_q * 256 * 4;
  u16* xbf = (u16*)p;                        p += (size_t)n_q * 256 * 2;
  u16* wtq = (u16*)p;                        p += 65536 * 2;
  u16* wtk = (u16*)p;                        p += 65536 * 2;
  u16* wtv = (u16*)p;                        p += 65536 * 2;
  u16* wto = (u16*)p;
  u16* ao = xbf;   // lifetimes disjoint

  hipLaunchKernelGGL(wt_kernel, dim3(128), dim3(256), 0, stream,
                     q_w, k_w, v_w, out_w, wtq, wtk, wtv, wto);
  hipLaunchKernelGGL(ln_kernel, dim3(n_q / 4), dim3(256), 0, stream,
                     query, norm_w, norm_b, xbf);
  hipLaunchKernelGGL(kv_gemm, dim3(TOT_ROWS / 64), dim3(256), 0, stream,
                     fm, wtk, wtv, rope, krot, vmap);
  hipLaunchKernelGGL(gemm_xw, dim3(n_q / 64, 8), dim3(256), 0, stream,
                     xbf, wtq, (const float*)nullptr, qraw);
  hipLaunchKernelGGL(attn2, dim3(n_q), dim3(256), 0, stream,
                     qraw, qsp, rope, qbo, nbo, krot, vmap, ao);
  hipLaunchKernelGGL(gemm_xw, dim3(n_q / 64, 8), dim3(256), 0, stream,
                     ao, wto, query, out);
}

// Round 4
// 281.229 us; speedup vs baseline: 1.6850x; 1.0954x over previous
//
#include <hip/hip_runtime.h>
#include <hip/hip_bf16.h>

typedef unsigned short u16;
typedef short short8 __attribute__((ext_vector_type(8)));
typedef float f32x4 __attribute__((ext_vector_type(4)));

// EMBED=256, NH=8, HD=32, NPAIR=16, K_PER_Q=164; levels 128,64,32,16
// compact rows/batch = 16384+4096+1024+256 = 21760
#define ROWS_PER_BATCH 21760
#define TOT_ROWS 43520

__device__ __forceinline__ u16 f2bf(float f){
  unsigned u = __builtin_bit_cast(unsigned, f);
  u += 0x7FFFu + ((u >> 16) & 1u);
  return (u16)(u >> 16);
}
__device__ __forceinline__ float bf2f(u16 h){
  return __builtin_bit_cast(float, ((unsigned)h) << 16);
}
__device__ __forceinline__ float bflo(unsigned u){ return __builtin_bit_cast(float, u << 16); }
__device__ __forceinline__ float bfhi(unsigned u){ return __builtin_bit_cast(float, u & 0xFFFF0000u); }
__device__ __forceinline__ unsigned pk2bf(float a, float b){
  __hip_bfloat162 h = __float22bfloat162_rn(make_float2(a, b));
  union { __hip_bfloat162 h2; unsigned u; } cv; cv.h2 = h; return cv.u;
}

// ---------- prep: weight pack (blocks 0..127) + LayerNorm (blocks 128..) ----------
// packed[((cg*8 + kk)*64 + lane)*8 + j] = W[kk*32 + (lane>>4)*8 + j][cg*16 + (lane&15)]
__global__ __launch_bounds__(256) void prep_kernel(
    const float* __restrict__ qw, const float* __restrict__ kw,
    const float* __restrict__ vw, const float* __restrict__ ow,
    const float* __restrict__ q, const float* __restrict__ nw,
    const float* __restrict__ nb,
    u16* __restrict__ wtq, u16* __restrict__ wtk,
    u16* __restrict__ wtv, u16* __restrict__ wto, u16* __restrict__ x){
  const int bx = blockIdx.x;
  const int t = threadIdx.x;
  if (bx < 128){
    int e = bx * 256 + t;                    // 0..32767 ; 8192 chunks/matrix
    int which = e >> 13;
    int r = e & 8191;
    int cg = r >> 9;
    int kk = (r >> 6) & 7;
    int lane = r & 63;
    int quad = lane >> 4, mn = lane & 15;
    const float* s = which == 0 ? qw : which == 1 ? kw : which == 2 ? vw : ow;
    u16* d       = which == 0 ? wtq : which == 1 ? wtk : which == 2 ? wtv : wto;
    const float* base = s + (kk * 32 + quad * 8) * 256 + cg * 16 + mn;
    float e8[8];
    #pragma unroll
    for (int j = 0; j < 8; ++j) e8[j] = base[j * 256];
    uint4 o = { pk2bf(e8[0], e8[1]), pk2bf(e8[2], e8[3]),
                pk2bf(e8[4], e8[5]), pk2bf(e8[6], e8[7]) };
    *(uint4*)(d + (size_t)r * 8) = o;
  } else {
    const int row = (bx - 128) * 4 + (t >> 6);
    const int lane = t & 63;
    const float4 v = *(const float4*)(q + (size_t)row * 256 + lane * 4);
    float s1 = v.x + v.y + v.z + v.w;
    float s2 = v.x*v.x + v.y*v.y + v.z*v.z + v.w*v.w;
    #pragma unroll
    for (int o = 32; o > 0; o >>= 1){
      s1 += __shfl_xor(s1, o);
      s2 += __shfl_xor(s2, o);
    }
    float mu = s1 * (1.0f / 256.0f);
    float var = s2 * (1.0f / 256.0f) - mu * mu;
    float rs = rsqrtf(var + 1e-5f);
    const float4 wv = *(const float4*)(nw + lane * 4);
    const float4 bv = *(const float4*)(nb + lane * 4);
    float o0 = (v.x - mu) * rs * wv.x + bv.x;
    float o1 = (v.y - mu) * rs * wv.y + bv.y;
    float o2 = (v.z - mu) * rs * wv.z + bv.z;
    float o3 = (v.w - mu) * rs * wv.w + bv.w;
    uint2 pk = { pk2bf(o0, o1), pk2bf(o2, o3) };
    *(uint2*)(x + (size_t)row * 256 + lane * 4) = pk;
  }
}

// ---------- K/V map projection, fused K-RoPE. BARRIER-FREE, per-wave. ----------
// grid (680, 2): y=0 -> K(rot), y=1 -> V. 256 thr = 4 waves; wave = 16 rows x 256 cols.
__global__ __launch_bounds__(256, 4) void kv_gemm(const float* __restrict__ fm,
        const u16* __restrict__ wtkp, const u16* __restrict__ wtvp,
        const float* __restrict__ rope,
        u16* __restrict__ krot, u16* __restrict__ vmap){
  __shared__ float slab[4][16][66];          // per-wave epilogue slabs
  __shared__ unsigned sh_cs[4][16][16];      // per-wave packed (cos,sin)

  const int t = threadIdx.x;
  const int row0 = blockIdx.x * 64;
  const int m = blockIdx.y;                  // 0 -> K, 1 -> V
  const u16* wtp = m ? wtvp : wtkp;
  u16* outp = m ? vmap : krot;

  const int b = row0 / ROWS_PER_BATCH;
  const int rr = row0 - b * ROWS_PER_BATCH;
  int l, loff;
  if (rr < 16384)      { l = 0; loff = 0; }
  else if (rr < 20480) { l = 1; loff = 16384; }
  else if (rr < 21504) { l = 2; loff = 20480; }
  else                 { l = 3; loff = 21504; }
  const int logW = 7 - l;
  const int Wm1 = (128 >> l) - 1;
  const int cell0 = rr - loff;
  const float* fmbase = fm + (size_t)(b * 4 + l) * (128 * 128 * 256);

  const int wv = t >> 6;
  const int lane = t & 63;
  const int mn = lane & 15;
  const int quad = lane >> 4;

  // A fragments straight from global (fp32 -> bf16 in regs); no LDS, no barrier.
  short8 af[8];
  {
    int cell = cell0 + wv * 16 + mn;
    int y = cell >> logW, x = cell & Wm1;
    const float* arow = fmbase + (((y << 7) + x) << 8) + quad * 8;
    #pragma unroll
    for (int kk = 0; kk < 8; ++kk){
      float4 a0 = *(const float4*)(arow + kk * 32);
      float4 a1 = *(const float4*)(arow + kk * 32 + 4);
      union { short8 s; uint4 u; } cv;
      cv.u = (uint4){ pk2bf(a0.x, a0.y), pk2bf(a0.z, a0.w),
                      pk2bf(a1.x, a1.y), pk2bf(a1.z, a1.w) };
      af[kk] = cv.s;
    }
  }

  // per-wave cos/sin table (K only): 16 rows x 16 pairs
  if (m == 0){
    #pragma unroll
    for (int i = 0; i < 4; ++i){
      int id = i * 64 + lane;                // 0..255
      int lr = id >> 4, p = id & 15;
      int cell = cell0 + wv * 16 + lr;
      int i0 = cell >> logW;
      int i1 = cell & Wm1;
      float fs = (float)(1 << l);
      float kx = ((float)i0 + 0.5f) * fs;
      float ky = ((float)i1 + 0.5f) * fs;
      float ang = kx * rope[p] + ky * rope[16 + p] + (float)l * rope[32 + p];
      sh_cs[wv][lr][p] = pk2bf(__cosf(ang), __sinf(ang));
    }
  }

  for (int cs2 = 0; cs2 < 4; ++cs2){
    const u16* wb = wtp + (size_t)((cs2 * 4 * 8) * 64 + lane) * 8;
    short8 bc[4], bn[4];
    #pragma unroll
    for (int tl = 0; tl < 4; ++tl)
      bc[tl] = *(const short8*)(wb + (size_t)(tl * 8) * 64 * 8);
    f32x4 acc[4];
    #pragma unroll
    for (int i = 0; i < 4; ++i) acc[i] = (f32x4){0.f, 0.f, 0.f, 0.f};
    #pragma unroll
    for (int kk = 0; kk < 8; ++kk){
      if (kk < 7){
        #pragma unroll
        for (int tl = 0; tl < 4; ++tl)
          bn[tl] = *(const short8*)(wb + (size_t)(tl * 8 + kk + 1) * 64 * 8);
      }
      #pragma unroll
      for (int tl = 0; tl < 4; ++tl)
        acc[tl] = __builtin_amdgcn_mfma_f32_16x16x32_bf16(af[kk], bc[tl], acc[tl], 0, 0, 0);
      #pragma unroll
      for (int tl = 0; tl < 4; ++tl) bc[tl] = bn[tl];
    }
    // per-wave epilogue: slab transpose -> (RoPE) -> coalesced bf16 store
    #pragma unroll
    for (int tl = 0; tl < 4; ++tl)
      #pragma unroll
      for (int r = 0; r < 4; ++r)
        slab[wv][quad * 4 + r][tl * 16 + mn] = acc[tl][r];
    #pragma unroll
    for (int i = 0; i < 8; ++i){
      int pi = i * 64 + lane;                // 0..511
      int row = pi >> 5;                     // 0..15
      int pl = pi & 31;                      // col-pair in strip
      float2 kv2 = *(const float2*)&slab[wv][row][pl * 2];
      unsigned o;
      if (m == 0){
        unsigned csn = sh_cs[wv][row][pl & 15];
        float c = bflo(csn), s = bfhi(csn);
        o = pk2bf(kv2.x * c - kv2.y * s, kv2.x * s + kv2.y * c);
      } else {
        o = pk2bf(kv2.x, kv2.y);
      }
      *(unsigned*)(outp + (size_t)(row0 + wv * 16 + row) * 256 + cs2 * 64 + pl * 2) = o;
    }
  }
}

// ---------- barrier-free MFMA GEMM: out[M][256] = A(bf16) @ WT (+resid) ----------
// grid (n_q/16, 4), 256 thr; wave w computes 16 rows x 16 cols (cg = y*4 + w)
__global__ __launch_bounds__(256) void gemm_xw(const u16* __restrict__ A,
        const u16* __restrict__ wt, const float* __restrict__ resid,
        float* __restrict__ out){
  const int t = threadIdx.x;
  const int row0 = blockIdx.x * 16;
  const int wv = t >> 6;
  const int lane = t & 63;
  const int mn = lane & 15;
  const int quad = lane >> 4;
  const int cg = blockIdx.y * 4 + wv;

  short8 af[8];
  {
    const u16* arow = A + (size_t)(row0 + mn) * 256 + quad * 8;
    #pragma unroll
    for (int kk = 0; kk < 8; ++kk)
      af[kk] = *(const short8*)(arow + kk * 32);
  }
  const u16* wb = wt + (size_t)((cg * 8) * 64 + lane) * 8;
  short8 bc = *(const short8*)wb;
  f32x4 acc = (f32x4){0.f, 0.f, 0.f, 0.f};
  #pragma unroll
  for (int kk = 0; kk < 8; ++kk){
    short8 bn;
    if (kk < 7) bn = *(const short8*)(wb + (size_t)(kk + 1) * 64 * 8);
    acc = __builtin_amdgcn_mfma_f32_16x16x32_bf16(af[kk], bc, acc, 0, 0, 0);
    bc = bn;
  }
  const int col = cg * 16 + mn;
  #pragma unroll
  for (int r = 0; r < 4; ++r){
    int row = row0 + quad * 4 + r;
    float val = acc[r];
    if (resid) val += resid[(size_t)row * 256 + col];
    out[(size_t)row * 256 + col] = val;
  }
}

// ---------- attention core: q-RoPE -> logits (head-parallel) -> softmax -> PV ----------
__global__ __launch_bounds__(256) void attn2(
    const float* __restrict__ qraw, const float* __restrict__ qsp,
    const float* __restrict__ rope, const int* __restrict__ qbo, int nbo,
    const u16* __restrict__ krot, const u16* __restrict__ vmap,
    u16* __restrict__ ao){
  __shared__ float sh_q[8][33];
  __shared__ float sh_lg[8][168];
  __shared__ int   sh_row[176];
  __shared__ float sh_inv[8];
  __shared__ float sh_pv[2][128][2];
  const int t = threadIdx.x;
  const int qi = blockIdx.x;

  int bidx = 0;
  for (int j = 1; j < nbo; ++j) if (qi >= qbo[j]) bidx = j;
  const float p0 = qsp[qi * 2 + 0];
  const float p1 = qsp[qi * 2 + 1];

  // q RoPE (scale 1/sqrt(32) folded in)
  {
    float qv = qraw[(size_t)qi * 256 + t];
    int p = (t & 31) >> 1;
    float ang = p0 * rope[p] + p1 * rope[16 + p];
    float c = __cosf(ang), s = __sinf(ang);
    float partner = __shfl_xor(qv, 1);
    float val = (t & 1) ? (partner * s + qv * c) : (qv * c - partner * s);
    sh_q[t >> 5][t & 31] = val * 0.17677669529663687f;
  }

  if (t < 164){
    int l, dy, dx, loff;
    if (t < 9)       { l = 0; int j = t;      dy = j / 3 - 1; dx = j % 3 - 1; loff = 0; }
    else if (t < 34) { l = 1; int j = t - 9;  dy = j / 5 - 2; dx = j % 5 - 2; loff = 16384; }
    else if (t < 83) { l = 2; int j = t - 34; dy = j / 7 - 3; dx = j % 7 - 3; loff = 20480; }
    else             { l = 3; int j = t - 83; dy = j / 9 - 4; dx = j % 9 - 4; loff = 21504; }
    float sc = 1.0f / (float)(1 << l);
    int i0 = (int)floorf(p0 * sc) + dy;
    int i1 = (int)floorf(p1 * sc) + dx;
    int W = 128 >> l;
    sh_row[t] = (i0 < 0 || i0 >= W || i1 < 0 || i1 >= W)
              ? -1 : bidx * ROWS_PER_BATCH + loff + (i0 << (7 - l)) + i1;
  }
  __syncthreads();

  // logits: thread = (key, head); 8 consecutive threads read one 512B K row
  const int h = t & 7;
  const int kbase = t >> 3;
  float qreg[32];
  #pragma unroll
  for (int d = 0; d < 32; ++d) qreg[d] = sh_q[h][d];
  for (int pass = 0; pass < 6; ++pass){
    int kk = pass * 32 + kbase;
    if (kk < 164){
      int row = sh_row[kk];
      float lg = -1e9f;
      if (row >= 0){
        const uint4* kp = (const uint4*)(krot + (size_t)row * 256 + h * 32);
        uint4 A0 = kp[0], A1 = kp[1], A2 = kp[2], A3 = kp[3];
        unsigned uu[16];
        uu[0]=A0.x; uu[1]=A0.y; uu[2]=A0.z; uu[3]=A0.w;
        uu[4]=A1.x; uu[5]=A1.y; uu[6]=A1.z; uu[7]=A1.w;
        uu[8]=A2.x; uu[9]=A2.y; uu[10]=A2.z; uu[11]=A2.w;
        uu[12]=A3.x; uu[13]=A3.y; uu[14]=A3.z; uu[15]=A3.w;
        lg = 0.f;
        #pragma unroll
        for (int j = 0; j < 16; ++j)
          lg += qreg[2*j] * bflo(uu[j]) + qreg[2*j+1] * bfhi(uu[j]);
      }
      sh_lg[h][kk] = lg;
    }
  }
  __syncthreads();

  // softmax: 32 lanes per head
  const int h3 = t >> 5;
  const int l32 = t & 31;
  float mx = -1e30f;
  for (int kk = l32; kk < 164; kk += 32) mx = fmaxf(mx, sh_lg[h3][kk]);
  #pragma unroll
  for (int o = 16; o > 0; o >>= 1) mx = fmaxf(mx, __shfl_xor(mx, o));
  float ssum = 0.f;
  for (int kk = l32; kk < 164; kk += 32){
    float e = __expf(sh_lg[h3][kk] - mx);   // invalid keys -> exactly 0
    sh_lg[h3][kk] = e;
    ssum += e;
  }
  #pragma unroll
  for (int o = 16; o > 0; o >>= 1) ssum += __shfl_xor(ssum, o);
  if (l32 == 0) sh_inv[h3] = 1.0f / ssum;
  __syncthreads();

  // PV: 2-way key split; thread owns a dim-pair (4B loads)
  {
    const int half = t >> 7;
    const int d2 = t & 127;
    const int hh = d2 >> 4;
    float a0 = 0.f, a1 = 0.f;
    const int k0 = half * 82;
    #pragma unroll 4
    for (int kk = k0; kk < k0 + 82; ++kk){
      int row = sh_row[kk];
      int rc = row < 0 ? 0 : row;
      unsigned vv = *(const unsigned*)(vmap + (size_t)rc * 256 + d2 * 2);
      float e = sh_lg[hh][kk];
      a0 += e * bflo(vv);
      a1 += e * bfhi(vv);
    }
    sh_pv[half][d2][0] = a0;
    sh_pv[half][d2][1] = a1;
  }
  __syncthreads();
  if (t < 128){
    const int hh = t >> 4;
    float inv = sh_inv[hh];
    float o0 = (sh_pv[0][t][0] + sh_pv[1][t][0]) * inv;
    float o1 = (sh_pv[0][t][1] + sh_pv[1][t][1]) * inv;
    *(unsigned*)(ao + (size_t)qi * 256 + t * 2) = pk2bf(o0, o1);
  }
}

extern "C" void kernel_launch(void* const* d_in, const int* in_sizes, int n_in,
                              void* d_out, int out_size, void* d_ws, size_t ws_size,
                              hipStream_t stream) {
  (void)n_in; (void)out_size; (void)ws_size;
  const float* query  = (const float*)d_in[0];
  const float* qsp    = (const float*)d_in[1];
  const float* fm     = (const float*)d_in[2];
  const float* norm_w = (const float*)d_in[3];
  const float* norm_b = (const float*)d_in[4];
  const float* q_w    = (const float*)d_in[5];
  const float* k_w    = (const float*)d_in[6];
  const float* v_w    = (const float*)d_in[7];
  const float* out_w  = (const float*)d_in[8];
  const float* rope   = (const float*)d_in[9];
  const int*   qbo    = (const int*)d_in[10];
  float* out = (float*)d_out;
  const int n_q = in_sizes[0] / 256;
  const int nbo = in_sizes[10];

  char* p = (char*)d_ws;
  u16* krot = (u16*)p;                       p += (size_t)TOT_ROWS * 256 * 2;
  u16* vmap = (u16*)p;                       p += (size_t)TOT_ROWS * 256 * 2;
  float* qraw = (float*)p;                   p += (size_t)n_q * 256 * 4;
  u16* xbf = (u16*)p;                        p += (size_t)n_q * 256 * 2;
  u16* wtq = (u16*)p;                        p += 65536 * 2;
  u16* wtk = (u16*)p;                        p += 65536 * 2;
  u16* wtv = (u16*)p;                        p += 65536 * 2;
  u16* wto = (u16*)p;
  u16* ao = xbf;   // lifetimes disjoint

  hipLaunchKernelGGL(prep_kernel, dim3(128 + n_q / 4), dim3(256), 0, stream,
                     q_w, k_w, v_w, out_w, query, norm_w, norm_b,
                     wtq, wtk, wtv, wto, xbf);
  hipLaunchKernelGGL(kv_gemm, dim3(TOT_ROWS / 64, 2), dim3(256), 0, stream,
                     fm, wtk, wtv, rope, krot, vmap);
  hipLaunchKernelGGL(gemm_xw, dim3(n_q / 16, 4), dim3(256), 0, stream,
                     xbf, wtq, (const float*)nullptr, qraw);
  hipLaunchKernelGGL(attn2, dim3(n_q), dim3(256), 0, stream,
                     qraw, qsp, rope, qbo, nbo, krot, vmap, ao);
  hipLaunchKernelGGL(gemm_xw, dim3(n_q / 16, 4), dim3(256), 0, stream,
                     ao, wto, query, out);
}

// Round 5
// 270.345 us; speedup vs baseline: 1.7528x; 1.0403x over previous
//
#include <hip/hip_runtime.h>
#include <hip/hip_bf16.h>

typedef unsigned short u16;
typedef short short8 __attribute__((ext_vector_type(8)));
typedef float f32x4 __attribute__((ext_vector_type(4)));

// EMBED=256, NH=8, HD=32, NPAIR=16, K_PER_Q=164; levels 128,64,32,16
// compact rows/batch = 16384+4096+1024+256 = 21760
#define ROWS_PER_BATCH 21760
#define TOT_ROWS 43520

__device__ __forceinline__ u16 f2bf(float f){
  unsigned u = __builtin_bit_cast(unsigned, f);
  u += 0x7FFFu + ((u >> 16) & 1u);
  return (u16)(u >> 16);
}
__device__ __forceinline__ float bf2f(u16 h){
  return __builtin_bit_cast(float, ((unsigned)h) << 16);
}
__device__ __forceinline__ float bflo(unsigned u){ return __builtin_bit_cast(float, u << 16); }
__device__ __forceinline__ float bfhi(unsigned u){ return __builtin_bit_cast(float, u & 0xFFFF0000u); }
__device__ __forceinline__ unsigned pk2bf(float a, float b){
  __hip_bfloat162 h = __float22bfloat162_rn(make_float2(a, b));
  union { __hip_bfloat162 h2; unsigned u; } cv; cv.h2 = h; return cv.u;
}

// ---------- prep: weight pack (blocks 0..127) + LayerNorm (blocks 128..) ----------
// packed[((cg*8 + kk)*64 + lane)*8 + j] = W[kk*32 + (lane>>4)*8 + j][cg*16 + (lane&15)]
__global__ __launch_bounds__(256) void prep_kernel(
    const float* __restrict__ qw, const float* __restrict__ kw,
    const float* __restrict__ vw, const float* __restrict__ ow,
    const float* __restrict__ q, const float* __restrict__ nw,
    const float* __restrict__ nb,
    u16* __restrict__ wtq, u16* __restrict__ wtk,
    u16* __restrict__ wtv, u16* __restrict__ wto, u16* __restrict__ x){
  const int bx = blockIdx.x;
  const int t = threadIdx.x;
  if (bx < 128){
    int e = bx * 256 + t;
    int which = e >> 13;
    int r = e & 8191;
    int cg = r >> 9;
    int kk = (r >> 6) & 7;
    int lane = r & 63;
    int quad = lane >> 4, mn = lane & 15;
    const float* s = which == 0 ? qw : which == 1 ? kw : which == 2 ? vw : ow;
    u16* d       = which == 0 ? wtq : which == 1 ? wtk : which == 2 ? wtv : wto;
    const float* base = s + (kk * 32 + quad * 8) * 256 + cg * 16 + mn;
    float e8[8];
    #pragma unroll
    for (int j = 0; j < 8; ++j) e8[j] = base[j * 256];
    uint4 o = { pk2bf(e8[0], e8[1]), pk2bf(e8[2], e8[3]),
                pk2bf(e8[4], e8[5]), pk2bf(e8[6], e8[7]) };
    *(uint4*)(d + (size_t)r * 8) = o;
  } else {
    const int row = (bx - 128) * 4 + (t >> 6);
    const int lane = t & 63;
    const float4 v = *(const float4*)(q + (size_t)row * 256 + lane * 4);
    float s1 = v.x + v.y + v.z + v.w;
    float s2 = v.x*v.x + v.y*v.y + v.z*v.z + v.w*v.w;
    #pragma unroll
    for (int o = 32; o > 0; o >>= 1){
      s1 += __shfl_xor(s1, o);
      s2 += __shfl_xor(s2, o);
    }
    float mu = s1 * (1.0f / 256.0f);
    float var = s2 * (1.0f / 256.0f) - mu * mu;
    float rs = rsqrtf(var + 1e-5f);
    const float4 wv = *(const float4*)(nw + lane * 4);
    const float4 bv = *(const float4*)(nb + lane * 4);
    float o0 = (v.x - mu) * rs * wv.x + bv.x;
    float o1 = (v.y - mu) * rs * wv.y + bv.y;
    float o2 = (v.z - mu) * rs * wv.z + bv.z;
    float o3 = (v.w - mu) * rs * wv.w + bv.w;
    uint2 pk = { pk2bf(o0, o1), pk2bf(o2, o3) };
    *(uint2*)(x + (size_t)row * 256 + lane * 4) = pk;
  }
}

// ---------- K+V map projection, fused K-RoPE. 1 wave/block, 16 rows, K AND V. ----------
// grid 2720 x 64 thr. Barrier-free; A fragments loaded once, reused for K and V.
__global__ __launch_bounds__(64, 4) void kv_gemm(const float* __restrict__ fm,
        const u16* __restrict__ wtkp, const u16* __restrict__ wtvp,
        const float* __restrict__ rope,
        u16* __restrict__ krot, u16* __restrict__ vmap){
  __shared__ float slab[16][66];
  __shared__ unsigned sh_cs[16][16];

  const int lane = threadIdx.x;
  const int row0 = blockIdx.x * 16;

  const int b = row0 / ROWS_PER_BATCH;
  const int rr = row0 - b * ROWS_PER_BATCH;
  int l, loff;
  if (rr < 16384)      { l = 0; loff = 0; }
  else if (rr < 20480) { l = 1; loff = 16384; }
  else if (rr < 21504) { l = 2; loff = 20480; }
  else                 { l = 3; loff = 21504; }
  const int logW = 7 - l;
  const int Wm1 = (128 >> l) - 1;
  const int cell0 = rr - loff;
  const float* fmbase = fm + (size_t)(b * 4 + l) * (128 * 128 * 256);

  const int mn = lane & 15;
  const int quad = lane >> 4;

  // A fragments straight from global (fp32 -> bf16 in regs)
  short8 af[8];
  {
    int cell = cell0 + mn;
    int y = cell >> logW, x = cell & Wm1;
    const float* arow = fmbase + (((y << 7) + x) << 8) + quad * 8;
    #pragma unroll
    for (int kk = 0; kk < 8; ++kk){
      float4 a0 = *(const float4*)(arow + kk * 32);
      float4 a1 = *(const float4*)(arow + kk * 32 + 4);
      union { short8 s; uint4 u; } cv;
      cv.u = (uint4){ pk2bf(a0.x, a0.y), pk2bf(a0.z, a0.w),
                      pk2bf(a1.x, a1.y), pk2bf(a1.z, a1.w) };
      af[kk] = cv.s;
    }
  }

  // cos/sin table: 16 rows x 16 pairs
  #pragma unroll
  for (int i = 0; i < 4; ++i){
    int id = i * 64 + lane;
    int lr = id >> 4, p = id & 15;
    int cell = cell0 + lr;
    int i0 = cell >> logW;
    int i1 = cell & Wm1;
    float fs = (float)(1 << l);
    float kx = ((float)i0 + 0.5f) * fs;
    float ky = ((float)i1 + 0.5f) * fs;
    float ang = kx * rope[p] + ky * rope[16 + p] + (float)l * rope[32 + p];
    sh_cs[lr][p] = pk2bf(__cosf(ang), __sinf(ang));
  }

  for (int m = 0; m < 2; ++m){
    const u16* wtp = m ? wtvp : wtkp;
    u16* outp = m ? vmap : krot;
    for (int cs2 = 0; cs2 < 4; ++cs2){
      const u16* wb = wtp + (size_t)((cs2 * 4 * 8) * 64 + lane) * 8;
      short8 bc[4], bn[4];
      #pragma unroll
      for (int tl = 0; tl < 4; ++tl)
        bc[tl] = *(const short8*)(wb + (size_t)(tl * 8) * 64 * 8);
      f32x4 acc[4];
      #pragma unroll
      for (int i = 0; i < 4; ++i) acc[i] = (f32x4){0.f, 0.f, 0.f, 0.f};
      #pragma unroll
      for (int kk = 0; kk < 8; ++kk){
        if (kk < 7){
          #pragma unroll
          for (int tl = 0; tl < 4; ++tl)
            bn[tl] = *(const short8*)(wb + (size_t)(tl * 8 + kk + 1) * 64 * 8);
        }
        #pragma unroll
        for (int tl = 0; tl < 4; ++tl)
          acc[tl] = __builtin_amdgcn_mfma_f32_16x16x32_bf16(af[kk], bc[tl], acc[tl], 0, 0, 0);
        #pragma unroll
        for (int tl = 0; tl < 4; ++tl) bc[tl] = bn[tl];
      }
      // wave-local epilogue: slab transpose -> (RoPE) -> coalesced bf16 store
      #pragma unroll
      for (int tl = 0; tl < 4; ++tl)
        #pragma unroll
        for (int r = 0; r < 4; ++r)
          slab[quad * 4 + r][tl * 16 + mn] = acc[tl][r];
      #pragma unroll
      for (int i = 0; i < 8; ++i){
        int pi = i * 64 + lane;
        int row = pi >> 5;
        int pl = pi & 31;
        float2 kv2 = *(const float2*)&slab[row][pl * 2];
        unsigned o;
        if (m == 0){
          unsigned csn = sh_cs[row][pl & 15];
          float c = bflo(csn), s = bfhi(csn);
          o = pk2bf(kv2.x * c - kv2.y * s, kv2.x * s + kv2.y * c);
        } else {
          o = pk2bf(kv2.x, kv2.y);
        }
        *(unsigned*)(outp + (size_t)(row0 + row) * 256 + cs2 * 64 + pl * 2) = o;
      }
    }
  }
}

// ---------- barrier-free MFMA GEMM: out[M][256] = A(bf16) @ WT (+resid) ----------
__global__ __launch_bounds__(256) void gemm_xw(const u16* __restrict__ A,
        const u16* __restrict__ wt, const float* __restrict__ resid,
        float* __restrict__ out){
  const int t = threadIdx.x;
  const int row0 = blockIdx.x * 16;
  const int wv = t >> 6;
  const int lane = t & 63;
  const int mn = lane & 15;
  const int quad = lane >> 4;
  const int cg = blockIdx.y * 4 + wv;

  short8 af[8];
  {
    const u16* arow = A + (size_t)(row0 + mn) * 256 + quad * 8;
    #pragma unroll
    for (int kk = 0; kk < 8; ++kk)
      af[kk] = *(const short8*)(arow + kk * 32);
  }
  const u16* wb = wt + (size_t)((cg * 8) * 64 + lane) * 8;
  short8 bc = *(const short8*)wb;
  f32x4 acc = (f32x4){0.f, 0.f, 0.f, 0.f};
  #pragma unroll
  for (int kk = 0; kk < 8; ++kk){
    short8 bn;
    if (kk < 7) bn = *(const short8*)(wb + (size_t)(kk + 1) * 64 * 8);
    acc = __builtin_amdgcn_mfma_f32_16x16x32_bf16(af[kk], bc, acc, 0, 0, 0);
    bc = bn;
  }
  const int col = cg * 16 + mn;
  #pragma unroll
  for (int r = 0; r < 4; ++r){
    int row = row0 + quad * 4 + r;
    float val = acc[r];
    if (resid) val += resid[(size_t)row * 256 + col];
    out[(size_t)row * 256 + col] = val;
  }
}

// ---------- attention core: ONE WAVE PER QUERY, zero barriers ----------
// grid n_q/4 x 256 thr. All LDS is wave-private; intra-wave RAW ordered by lgkmcnt.
__global__ __launch_bounds__(256) void attn3(
    const float* __restrict__ qraw, const float* __restrict__ qsp,
    const float* __restrict__ rope, const int* __restrict__ qbo, int nbo,
    const u16* __restrict__ krot, const u16* __restrict__ vmap,
    u16* __restrict__ ao){
  __shared__ float sh_q[4][8][33];
  __shared__ float sh_lg[4][168][8];
  __shared__ int   sh_row[4][168];
  __shared__ float sh_inv[4][8];
  const int t = threadIdx.x;
  const int w = t >> 6;
  const int lane = t & 63;
  const int qi = blockIdx.x * 4 + w;

  int bidx = 0;
  for (int j = 1; j < nbo; ++j) if (qi >= qbo[j]) bidx = j;
  const float p0 = qsp[qi * 2 + 0];
  const float p1 = qsp[qi * 2 + 1];

  // q RoPE (1/sqrt(32) folded); 4 iters x 64 lanes cover 256 dims
  #pragma unroll
  for (int it = 0; it < 4; ++it){
    int d = it * 64 + lane;
    float qv = qraw[(size_t)qi * 256 + d];
    int p = (d & 31) >> 1;
    float ang = p0 * rope[p] + p1 * rope[16 + p];
    float c = __cosf(ang), s = __sinf(ang);
    float partner = __shfl_xor(qv, 1);
    float val = (d & 1) ? (partner * s + qv * c) : (qv * c - partner * s);
    sh_q[w][d >> 5][d & 31] = val * 0.17677669529663687f;
  }

  // key rows + validity
  #pragma unroll
  for (int it = 0; it < 3; ++it){
    int kk = it * 64 + lane;
    if (kk < 164){
      int l, dy, dx, loff;
      if (kk < 9)       { l = 0; int j = kk;      dy = j / 3 - 1; dx = j % 3 - 1; loff = 0; }
      else if (kk < 34) { l = 1; int j = kk - 9;  dy = j / 5 - 2; dx = j % 5 - 2; loff = 16384; }
      else if (kk < 83) { l = 2; int j = kk - 34; dy = j / 7 - 3; dx = j % 7 - 3; loff = 20480; }
      else              { l = 3; int j = kk - 83; dy = j / 9 - 4; dx = j % 9 - 4; loff = 21504; }
      float sc = 1.0f / (float)(1 << l);
      int i0 = (int)floorf(p0 * sc) + dy;
      int i1 = (int)floorf(p1 * sc) + dx;
      int W = 128 >> l;
      sh_row[w][kk] = (i0 < 0 || i0 >= W || i1 < 0 || i1 >= W)
                ? -1 : bidx * ROWS_PER_BATCH + loff + (i0 << (7 - l)) + i1;
    }
  }

  // logits: lane = (ksub, h); wave reads 8 contiguous 512B K rows per pass
  const int h = lane & 7;
  const int ksub = lane >> 3;
  float qreg[32];
  #pragma unroll
  for (int j = 0; j < 32; ++j) qreg[j] = sh_q[w][h][j];
  for (int pass = 0; pass < 21; ++pass){
    int kk = pass * 8 + ksub;
    if (kk < 164){
      int row = sh_row[w][kk];
      float lg = -1e9f;
      if (row >= 0){
        const uint4* kp = (const uint4*)(krot + (size_t)row * 256 + h * 32);
        uint4 A0 = kp[0], A1 = kp[1], A2 = kp[2], A3 = kp[3];
        unsigned uu[16];
        uu[0]=A0.x; uu[1]=A0.y; uu[2]=A0.z; uu[3]=A0.w;
        uu[4]=A1.x; uu[5]=A1.y; uu[6]=A1.z; uu[7]=A1.w;
        uu[8]=A2.x; uu[9]=A2.y; uu[10]=A2.z; uu[11]=A2.w;
        uu[12]=A3.x; uu[13]=A3.y; uu[14]=A3.z; uu[15]=A3.w;
        lg = 0.f;
        #pragma unroll
        for (int j = 0; j < 16; ++j)
          lg += qreg[2*j] * bflo(uu[j]) + qreg[2*j+1] * bfhi(uu[j]);
      }
      sh_lg[w][kk][h] = lg;
    }
  }

  // softmax: 8 lanes per head (xor 8/16/32 butterflies preserve h)
  float mx = -1e30f;
  for (int kk = ksub; kk < 164; kk += 8) mx = fmaxf(mx, sh_lg[w][kk][h]);
  #pragma unroll
  for (int o = 8; o < 64; o <<= 1) mx = fmaxf(mx, __shfl_xor(mx, o));
  float ssum = 0.f;
  for (int kk = ksub; kk < 164; kk += 8){
    float e = __expf(sh_lg[w][kk][h] - mx);    // invalid keys -> exactly 0
    sh_lg[w][kk][h] = e;
    ssum += e;
  }
  #pragma unroll
  for (int o = 8; o < 64; o <<= 1) ssum += __shfl_xor(ssum, o);
  if (ksub == 0) sh_inv[w][h] = 1.0f / ssum;

  // PV: lane owns 4 dims (8B coalesced V loads; 512B/wave per key)
  const int hh = lane >> 3;
  float a0 = 0.f, a1 = 0.f, a2 = 0.f, a3 = 0.f;
  #pragma unroll 4
  for (int kk = 0; kk < 164; ++kk){
    int row = sh_row[w][kk];
    int rc = row < 0 ? 0 : row;
    uint2 vv = *(const uint2*)(vmap + (size_t)rc * 256 + lane * 4);
    float e = sh_lg[w][kk][hh];
    a0 += e * bflo(vv.x);
    a1 += e * bfhi(vv.x);
    a2 += e * bflo(vv.y);
    a3 += e * bfhi(vv.y);
  }
  float inv = sh_inv[w][hh];
  uint2 o = { pk2bf(a0 * inv, a1 * inv), pk2bf(a2 * inv, a3 * inv) };
  *(uint2*)(ao + (size_t)qi * 256 + lane * 4) = o;
}

extern "C" void kernel_launch(void* const* d_in, const int* in_sizes, int n_in,
                              void* d_out, int out_size, void* d_ws, size_t ws_size,
                              hipStream_t stream) {
  (void)n_in; (void)out_size; (void)ws_size;
  const float* query  = (const float*)d_in[0];
  const float* qsp    = (const float*)d_in[1];
  const float* fm     = (const float*)d_in[2];
  const float* norm_w = (const float*)d_in[3];
  const float* norm_b = (const float*)d_in[4];
  const float* q_w    = (const float*)d_in[5];
  const float* k_w    = (const float*)d_in[6];
  const float* v_w    = (const float*)d_in[7];
  const float* out_w  = (const float*)d_in[8];
  const float* rope   = (const float*)d_in[9];
  const int*   qbo    = (const int*)d_in[10];
  float* out = (float*)d_out;
  const int n_q = in_sizes[0] / 256;
  const int nbo = in_sizes[10];

  char* p = (char*)d_ws;
  u16* krot = (u16*)p;                       p += (size_t)TOT_ROWS * 256 * 2;
  u16* vmap = (u16*)p;                       p += (size_t)TOT_ROWS * 256 * 2;
  float* qraw = (float*)p;                   p += (size_t)n_q * 256 * 4;
  u16* xbf = (u16*)p;                        p += (size_t)n_q * 256 * 2;
  u16* wtq = (u16*)p;                        p += 65536 * 2;
  u16* wtk = (u16*)p;                        p += 65536 * 2;
  u16* wtv = (u16*)p;                        p += 65536 * 2;
  u16* wto = (u16*)p;
  u16* ao = xbf;   // lifetimes disjoint

  hipLaunchKernelGGL(prep_kernel, dim3(128 + n_q / 4), dim3(256), 0, stream,
                     q_w, k_w, v_w, out_w, query, norm_w, norm_b,
                     wtq, wtk, wtv, wto, xbf);
  hipLaunchKernelGGL(kv_gemm, dim3(TOT_ROWS / 16), dim3(64), 0, stream,
                     fm, wtk, wtv, rope, krot, vmap);
  hipLaunchKernelGGL(gemm_xw, dim3(n_q / 16, 4), dim3(256), 0, stream,
                     xbf, wtq, (const float*)nullptr, qraw);
  hipLaunchKernelGGL(attn3, dim3(n_q / 4), dim3(256), 0, stream,
                     qraw, qsp, rope, qbo, nbo, krot, vmap, ao);
  hipLaunchKernelGGL(gemm_xw, dim3(n_q / 16, 4), dim3(256), 0, stream,
                     ao, wto, query, out);
}